// Round 7
// baseline (132.306 us; speedup 1.0000x reference)
//
#include <hip/hip_runtime.h>
#include <hip/hip_bf16.h>
#include <stdint.h>
#include <math.h>

#define NB 32
#define NF 512
#define NH 8
#define ND 64
#define NS 256
#define TOPK 51
#define STILE 32
#define LDSF 537   // swizzled row stride; OFF(f)=f+8*(f>>7)

__device__ __forceinline__ float wave_sum_f32(float v) {
#pragma unroll
  for (int o = 32; o > 0; o >>= 1) v += __shfl_xor(v, o, 64);
  return v;
}

__device__ __forceinline__ int lane_prefix(unsigned long long m) {
  return __builtin_amdgcn_mbcnt_hi((unsigned)(m >> 32),
         __builtin_amdgcn_mbcnt_lo((unsigned)m, 0u));
}

__device__ __forceinline__ unsigned f32key(float x) {
  unsigned b = __float_as_uint(x);
  return (b & 0x80000000u) ? ~b : (b | 0x80000000u);
}

// Bit-exact numpy pairwise_sum(n=512) on a swizzled LDS row.
// Element f at word OFF(f)=f+8*(f>>7); 128-block k contiguous at 136k.
// Chain (k,c): banks (8k+c+8m)%32 cover all 32 -> conflict-free.
__device__ __forceinline__ float np_pairwise_sum_512(const float* __restrict__ row, int lane) {
  const int c2 = lane & 31;
  const int k  = c2 >> 3;
  const int c  = c2 & 7;
  const float* blk = row + 136 * k;
  float r = blk[c];
#pragma unroll
  for (int m = 1; m < 16; ++m) r += blk[c + 8 * m];   // exact sequential order
  float s = r + __shfl_xor(r, 1, 64);
  s = s + __shfl_xor(s, 2, 64);
  s = s + __shfl_xor(s, 4, 64);
  float u = s + __shfl_xor(s, 8, 64);
  u = u + __shfl_xor(u, 16, 64);
  return u;
}

// Guarded exact top-k threshold: T = largest key with count(>=T) >= TOPK.
// Bracket [lo,hi] is a heuristic; guards restore the invariant when it misses.
__device__ __forceinline__ void solve_topk(const unsigned key[8], unsigned lo, unsigned hi,
                                           unsigned& T, int& cnt) {
  auto countGE = [&key](unsigned thr) -> int {
    int c = 0;
#pragma unroll
    for (int j = 0; j < 8; ++j) c += __popcll(__ballot(key[j] >= thr));
    return c;
  };
  if (hi <= lo) hi = lo + 1;
  int cl = countGE(lo);
  unsigned step = hi - lo;
  while (cl < TOPK) {                 // bracket entirely above threshold (rare)
    hi = lo;
    lo = (lo >= step) ? (lo - step) : 0u;
    step <<= 1;
    cl = countGE(lo);
  }
  if (cl == TOPK) { T = lo; cnt = cl; return; }
  int ch = countGE(hi);
  while (ch >= TOPK && hi != 0xFFFFFFFFu) {   // bracket below threshold (rare)
    lo = hi; cl = ch;
    unsigned nh = hi + step;
    if (nh < hi) nh = 0xFFFFFFFFu;
    hi = nh; step <<= 1;
    ch = countGE(hi);
  }
  if (ch >= TOPK) { T = hi; cnt = ch; return; }
  while (lo < hi) {
    unsigned mid = hi - ((hi - lo) >> 1);
    int cm = countGE(mid);
    if (cm >= TOPK) { lo = mid; cl = cm; if (cm == TOPK) break; }
    else hi = mid - 1;
  }
  T = lo; cnt = cl;
}

// Per-(h,s): exact softplus(beta) + Gaussian-model bracket for the top-k key
// threshold. Bracket is a HEURISTIC (guarded in main kernel); beta is exact.
__global__ __launch_bounds__(256)
void prep_kernel(const float* __restrict__ bp, const float* __restrict__ alpha,
                 float* __restrict__ betaf, unsigned* __restrict__ klo,
                 unsigned* __restrict__ khi) {
  const int gid  = blockIdx.x * 256 + threadIdx.x;
  const int hs   = gid >> 6;
  const int lane = gid & 63;
  if (hs >= NH * NS) return;
  const float scalef = (float)0.04419417382415922;
  const float* ar = alpha + (size_t)hs * NF;
  float s1 = 0.f, s2 = 0.f;
#pragma unroll
  for (int j = 0; j < 8; ++j) {
    float v = ar[lane + 64 * j] * scalef;
    s1 += v; s2 = fmaf(v, v, s2);
  }
  s1 = wave_sum_f32(s1); s2 = wave_sum_f32(s2);
  const float mean = s1 * (1.f / 512.f);
  float var = s2 * (1.f / 512.f) - mean * mean;
  if (var < 0.f) var = 0.f;
  const double e = exp((double)bp[hs]);        // numpy softplus on f32 input
  const float beta = (float)log1p(e);
  const float sig  = sqrtf(var + beta * beta);
  const float that = fmaf(1.281552f, sig, mean);   // 90.04th pct (top 51/512)
  const float w    = 0.30f * sig;
  if (lane == 0) {
    betaf[hs] = beta;
    klo[hs] = f32key(that - w);
    khi[hs] = f32key(that + w);
  }
}

__global__ __launch_bounds__(1024, 8)   // VGPR cap 64 -> 2 blocks (32 waves)/CU
void gating_attention_kernel(const float* __restrict__ vals,   // [B,F,H,D]
                             const float* __restrict__ dlg,    // [B,F,H,S]
                             const float* __restrict__ alpha,  // [H,S,F]
                             const float* __restrict__ betap,  // [H,S,1]
                             const float* __restrict__ betaf,  // [H*S] softplus (or null)
                             const unsigned* __restrict__ klo, // [H*S] bracket lo
                             const unsigned* __restrict__ khi, // [H*S] bracket hi
                             float* __restrict__ out)          // [B,S,H,D]
{
#pragma clang fp contract(off)       // numpy does mul THEN add; forbid fma fusion
  __shared__ float dl_t[STILE * LDSF];   // 68.7 KB; pairs reuse dead row space

  const int blk  = blockIdx.x;       // bh in low 8 bits -> XCD = h (L2 locality)
  const int bh   = blk & 255;
  const int t    = blk >> 8;         // 0..7
  const int b    = bh >> 3;
  const int h    = bh & 7;
  const int s0   = t * STILE;
  const int tid  = threadIdx.x;
  const int w    = tid >> 6;
  const int lane = tid & 63;
  const float scalef = (float)0.04419417382415922;   // f32(1/sqrt(512))

  // ---- stage data_logits tile [32 s][512 f], transposed, full 64B lines ----
#pragma unroll
  for (int cc = 0; cc < 4; ++cc) {
    int i  = cc * 1024 + tid;         // 0..4095
    int f  = i >> 3;                  // 0..511
    int sg = (i & 7) << 2;            // 0,4,...,28
    int fo = f + ((f >> 7) << 3);
    const float4 v4 = *reinterpret_cast<const float4*>(
        dlg + ((((size_t)b * NF + f) * NH + h) * NS + (size_t)(s0 + sg)));
    dl_t[(sg + 0) * LDSF + fo] = v4.x;
    dl_t[(sg + 1) * LDSF + fo] = v4.y;
    dl_t[(sg + 2) * LDSF + fo] = v4.z;
    dl_t[(sg + 3) * LDSF + fo] = v4.w;
  }
  __syncthreads();

  // ---- two rows per wave: r0=2w, r1=2w+1 (independent -> ILP 2) ----
  const int r0 = 2 * w, r1 = 2 * w + 1;
  const int sA = s0 + r0, sB = s0 + r1;
  const int hsA = h * NS + sA, hsB = h * NS + sB;
  float* rowA = dl_t + r0 * LDSF;
  float* rowB = dl_t + r1 * LDSF;

  // lane->f mapping: f(g,jj) = 256*g + 4*lane + jj
  const int fb0 = 4 * lane;
  const int off0 = fb0 + ((fb0 >> 7) << 3);
  const int fb1 = 256 + 4 * lane;
  const int off1 = fb1 + ((fb1 >> 7) << 3);

  const float4 aA0 = *reinterpret_cast<const float4*>(alpha + (size_t)hsA * NF + fb0);
  const float4 aA1 = *reinterpret_cast<const float4*>(alpha + (size_t)hsA * NF + fb1);
  const float4 aB0 = *reinterpret_cast<const float4*>(alpha + (size_t)hsB * NF + fb0);
  const float4 aB1 = *reinterpret_cast<const float4*>(alpha + (size_t)hsB * NF + fb1);
  const float4 xA0 = *reinterpret_cast<const float4*>(rowA + off0);
  const float4 xA1 = *reinterpret_cast<const float4*>(rowA + off1);
  const float4 xB0 = *reinterpret_cast<const float4*>(rowB + off0);
  const float4 xB1 = *reinterpret_cast<const float4*>(rowB + off1);

  float xA[8] = {xA0.x, xA0.y, xA0.z, xA0.w, xA1.x, xA1.y, xA1.z, xA1.w};
  float xB[8] = {xB0.x, xB0.y, xB0.z, xB0.w, xB1.x, xB1.y, xB1.z, xB1.w};
  float aA[8] = {aA0.x, aA0.y, aA0.z, aA0.w, aA1.x, aA1.y, aA1.z, aA1.w};
  float aB[8] = {aB0.x, aB0.y, aB0.z, aB0.w, aB1.x, aB1.y, aB1.z, aB1.w};

  // ---- mu (both rows: chains interleave) ----
  const float S1A = np_pairwise_sum_512(rowA, lane);
  const float S1B = np_pairwise_sum_512(rowB, lane);
  const float muA = S1A * (1.0f / 512.0f);
  const float muB = S1B * (1.0f / 512.0f);

  // ---- var ----
  float tvA[8], tvB[8];
#pragma unroll
  for (int j = 0; j < 8; ++j) { tvA[j] = xA[j] - muA; tvB[j] = xB[j] - muB; }
  *reinterpret_cast<float4*>(rowA + off0) =
      make_float4(tvA[0]*tvA[0], tvA[1]*tvA[1], tvA[2]*tvA[2], tvA[3]*tvA[3]);
  *reinterpret_cast<float4*>(rowA + off1) =
      make_float4(tvA[4]*tvA[4], tvA[5]*tvA[5], tvA[6]*tvA[6], tvA[7]*tvA[7]);
  *reinterpret_cast<float4*>(rowB + off0) =
      make_float4(tvB[0]*tvB[0], tvB[1]*tvB[1], tvB[2]*tvB[2], tvB[3]*tvB[3]);
  *reinterpret_cast<float4*>(rowB + off1) =
      make_float4(tvB[4]*tvB[4], tvB[5]*tvB[5], tvB[6]*tvB[6], tvB[7]*tvB[7]);
  const float S2A = np_pairwise_sum_512(rowA, lane);
  const float S2B = np_pairwise_sum_512(rowB, lane);
  const float stdA = sqrtf(S2A * (1.0f / 512.0f) + 1e-6f) + 1e-6f;
  const float stdB = sqrtf(S2B * (1.0f / 512.0f) + 1e-6f) + 1e-6f;

  // ---- beta ----
  float betaA, betaB;
  if (betaf) { betaA = betaf[hsA]; betaB = betaf[hsB]; }
  else {
    betaA = (float)log1p(exp((double)betap[hsA]));
    betaB = (float)log1p(exp((double)betap[hsB]));
  }

  // ---- logits: numpy f32 op order; divide via uniform f64 reciprocal ----
  const double rdA = 1.0 / (double)stdA;
  const double rdB = 1.0 / (double)stdB;
  float lgA[8], lgB[8];
  unsigned keyA[8], keyB[8];
#pragma unroll
  for (int j = 0; j < 8; ++j) {
    float zA = (float)((double)tvA[j] * rdA);   // == IEEE f32 div (2^-29 corner)
    float zB = (float)((double)tvB[j] * rdB);
    float lA = aA[j] * scalef + betaA * zA;     // contract(off): mul,mul,add exact
    float lB = aB[j] * scalef + betaB * zB;
    lgA[j] = lA; lgB[j] = lB;
    keyA[j] = f32key(lA); keyB[j] = f32key(lB);
  }

  // ---- exact thresholds (bracket model or min/max fallback) ----
  unsigned loA, hiA, loB, hiB;
  if (klo) {
    loA = klo[hsA]; hiA = khi[hsA];
    loB = klo[hsB]; hiB = khi[hsB];
  } else {
    unsigned kmin = keyA[0], kmax = keyA[0];
#pragma unroll
    for (int j = 1; j < 8; ++j) {
      kmax = keyA[j] > kmax ? keyA[j] : kmax;
      kmin = keyA[j] < kmin ? keyA[j] : kmin;
    }
#pragma unroll
    for (int j = 0; j < 8; ++j) {
      kmax = keyB[j] > kmax ? keyB[j] : kmax;
      kmin = keyB[j] < kmin ? keyB[j] : kmin;
    }
#pragma unroll
    for (int o = 32; o > 0; o >>= 1) {
      unsigned om = (unsigned)__shfl_xor((int)kmax, o, 64);
      unsigned on = (unsigned)__shfl_xor((int)kmin, o, 64);
      kmax = om > kmax ? om : kmax;
      kmin = on < kmin ? on : kmin;
    }
    loA = loB = kmin; hiA = hiB = kmax;
  }
  unsigned TA, TB; int cntA, cntB;
  solve_topk(keyA, loA, hiA, TA, cntA);
  solve_topk(keyB, loB, hiB, TB, cntB);

  // ---- keep masks; tie resolution only when needed ----
  bool keepA[8], keepB[8];
  if (cntA == TOPK) {
#pragma unroll
    for (int j = 0; j < 8; ++j) keepA[j] = (keyA[j] >= TA);
  } else {
    int g = 0;
#pragma unroll
    for (int j = 0; j < 8; ++j) g += __popcll(__ballot(keyA[j] > TA));
    const int need = TOPK - g;
    int cumt = 0;
#pragma unroll
    for (int j = 0; j < 8; ++j) {
      unsigned long long meq = __ballot(keyA[j] == TA);
      int tr = cumt + lane_prefix(meq);
      cumt += __popcll(meq);
      keepA[j] = (keyA[j] > TA) || ((keyA[j] == TA) && (tr < need));
    }
  }
  if (cntB == TOPK) {
#pragma unroll
    for (int j = 0; j < 8; ++j) keepB[j] = (keyB[j] >= TB);
  } else {
    int g = 0;
#pragma unroll
    for (int j = 0; j < 8; ++j) g += __popcll(__ballot(keyB[j] > TB));
    const int need = TOPK - g;
    int cumt = 0;
#pragma unroll
    for (int j = 0; j < 8; ++j) {
      unsigned long long meq = __ballot(keyB[j] == TB);
      int tr = cumt + lane_prefix(meq);
      cumt += __popcll(meq);
      keepB[j] = (keyB[j] > TB) || ((keyB[j] == TB) && (tr < need));
    }
  }

  unsigned tbA = (TA & 0x80000000u) ? (TA ^ 0x80000000u) : ~TA;
  unsigned tbB = (TB & 0x80000000u) ? (TB ^ 0x80000000u) : ~TB;
  const float thrA = __uint_as_float(tbA);
  const float thrB = __uint_as_float(tbB);

  // ---- softmax numerators ----
  float pA[8], pB[8];
  float zsA = 0.0f, zsB = 0.0f;
#pragma unroll
  for (int j = 0; j < 8; ++j) {
    float eA = keepA[j] ? __expf(lgA[j] - thrA) : 0.0f;
    float eB = keepB[j] ? __expf(lgB[j] - thrB) : 0.0f;
    pA[j] = eA; pB[j] = eB;
    zsA += eA; zsB += eB;
  }
  zsA = wave_sum_f32(zsA);
  zsB = wave_sum_f32(zsB);
  const float rzA = 1.0f / zsA;
  const float rzB = 1.0f / zsB;

  // ---- compact kept (byte-offset, p) pairs into each row's dead LDS space ----
  // Row data is dead after S2; rows are wave-private so no barrier needed.
  uint2* prA = (uint2*)(dl_t + ((r0 * LDSF + 1) & ~1));
  uint2* prB = (uint2*)(dl_t + ((r1 * LDSF + 1) & ~1));
  int baseA = 0, baseB = 0;
#pragma unroll
  for (int j = 0; j < 8; ++j) {
    unsigned f = (unsigned)(((j >> 2) << 8) + 4 * lane + (j & 3));
    unsigned long long mkA = __ballot(keepA[j]);
    int idxA = baseA + lane_prefix(mkA);
    if (keepA[j]) prA[idxA] = make_uint2(f << 11, __float_as_uint(pA[j]));
    baseA += __popcll(mkA);
    unsigned long long mkB = __ballot(keepB[j]);
    int idxB = baseB + lane_prefix(mkB);
    if (keepB[j]) prB[idxB] = make_uint2(f << 11, __float_as_uint(pB[j]));
    baseB += __popcll(mkB);
  }
  if (lane == TOPK) {
    prA[TOPK] = make_uint2(0u, 0u);
    prB[TOPK] = make_uint2(0u, 0u);
  }
  const int nk = (TOPK + 3) & ~3;    // 52

  // ---- sparse PV gather: both rows interleaved, 8 loads in flight ----
  const char* vbase = (const char*)(vals + (((size_t)b * NF) * NH + h) * ND) + 4 * lane;
  float aA0c = 0.f, aA1c = 0.f, aA2c = 0.f, aA3c = 0.f;
  float aB0c = 0.f, aB1c = 0.f, aB2c = 0.f, aB3c = 0.f;
  for (int k0 = 0; k0 < nk; k0 += 4) {
    uint2 eA0 = prA[k0 + 0], eA1 = prA[k0 + 1], eA2 = prA[k0 + 2], eA3 = prA[k0 + 3];
    uint2 eB0 = prB[k0 + 0], eB1 = prB[k0 + 1], eB2 = prB[k0 + 2], eB3 = prB[k0 + 3];
    float vA0 = *(const float*)(vbase + eA0.x);
    float vA1 = *(const float*)(vbase + eA1.x);
    float vA2 = *(const float*)(vbase + eA2.x);
    float vA3 = *(const float*)(vbase + eA3.x);
    float vB0 = *(const float*)(vbase + eB0.x);
    float vB1 = *(const float*)(vbase + eB1.x);
    float vB2 = *(const float*)(vbase + eB2.x);
    float vB3 = *(const float*)(vbase + eB3.x);
    aA0c = fmaf(__uint_as_float(eA0.y), vA0, aA0c);
    aA1c = fmaf(__uint_as_float(eA1.y), vA1, aA1c);
    aA2c = fmaf(__uint_as_float(eA2.y), vA2, aA2c);
    aA3c = fmaf(__uint_as_float(eA3.y), vA3, aA3c);
    aB0c = fmaf(__uint_as_float(eB0.y), vB0, aB0c);
    aB1c = fmaf(__uint_as_float(eB1.y), vB1, aB1c);
    aB2c = fmaf(__uint_as_float(eB2.y), vB2, aB2c);
    aB3c = fmaf(__uint_as_float(eB3.y), vB3, aB3c);
  }
  const float accA = (aA0c + aA1c) + (aA2c + aA3c);
  const float accB = (aB0c + aB1c) + (aB2c + aB3c);

  out[(((size_t)b * NS + sA) * NH + h) * ND + lane] = accA * rzA;
  out[(((size_t)b * NS + sB) * NH + h) * ND + lane] = accB * rzB;
}

extern "C" void kernel_launch(void* const* d_in, const int* in_sizes, int n_in,
                              void* d_out, int out_size, void* d_ws, size_t ws_size,
                              hipStream_t stream) {
  const float* vals  = (const float*)d_in[0];
  const float* dlg   = (const float*)d_in[1];
  const float* alpha = (const float*)d_in[2];
  const float* betap = (const float*)d_in[3];
  float* out = (float*)d_out;

  float* betaf = nullptr; unsigned* klo = nullptr; unsigned* khi = nullptr;
  const size_t need = (size_t)(NH * NS) * 12;   // beta + klo + khi
  if (ws_size >= need) {
    betaf = (float*)d_ws;
    klo   = (unsigned*)((char*)d_ws + (size_t)(NH * NS) * 4);
    khi   = (unsigned*)((char*)d_ws + (size_t)(NH * NS) * 8);
    prep_kernel<<<(NH * NS * 64) / 256, 256, 0, stream>>>(betap, alpha, betaf, klo, khi);
  }

  dim3 grid(NB * NH * (NS / STILE));   // 2048 blocks: one per (b,h,32-row tile)
  dim3 block(1024);
  gating_attention_kernel<<<grid, block, 0, stream>>>(vals, dlg, alpha, betap,
                                                      betaf, klo, khi, out);
}

// Round 8
// 113.561 us; speedup vs baseline: 1.1651x; 1.1651x over previous
//
#include <hip/hip_runtime.h>
#include <hip/hip_bf16.h>
#include <stdint.h>
#include <math.h>

#define NB 32
#define NF 512
#define NH 8
#define ND 64
#define NS 256
#define TOPK 51
#define STILE 16
#define LDSF 537   // swizzled row stride; OFF(f)=f+8*(f>>7)

__device__ __forceinline__ float wave_sum_f32(float v) {
#pragma unroll
  for (int o = 32; o > 0; o >>= 1) v += __shfl_xor(v, o, 64);
  return v;
}

__device__ __forceinline__ int lane_prefix(unsigned long long m) {
  return __builtin_amdgcn_mbcnt_hi((unsigned)(m >> 32),
         __builtin_amdgcn_mbcnt_lo((unsigned)m, 0u));
}

__device__ __forceinline__ unsigned f32key(float x) {
  unsigned b = __float_as_uint(x);
  return (b & 0x80000000u) ? ~b : (b | 0x80000000u);
}

// Bit-exact numpy pairwise_sum(n=512) on a swizzled LDS row.
// Element f at word OFF(f)=f+8*(f>>7); 128-block k contiguous at 136k.
// Chain (k,c): banks (8k+c+8m)%32 cover all 32 -> conflict-free.
__device__ __forceinline__ float np_pairwise_sum_512(const float* __restrict__ row, int lane) {
  const int c2 = lane & 31;
  const int k  = c2 >> 3;
  const int c  = c2 & 7;
  const float* blk = row + 136 * k;
  float r = blk[c];
#pragma unroll
  for (int m = 1; m < 16; ++m) r += blk[c + 8 * m];   // exact sequential order
  float s = r + __shfl_xor(r, 1, 64);
  s = s + __shfl_xor(s, 2, 64);
  s = s + __shfl_xor(s, 4, 64);
  float u = s + __shfl_xor(s, 8, 64);
  u = u + __shfl_xor(u, 16, 64);
  return u;
}

// Per-(h,s): exact softplus(beta) + Gaussian-model bracket for the top-k key
// threshold. Bracket is a HEURISTIC (guarded in main kernel); beta is exact.
__global__ __launch_bounds__(256)
void prep_kernel(const float* __restrict__ bp, const float* __restrict__ alpha,
                 float* __restrict__ betaf, unsigned* __restrict__ klo,
                 unsigned* __restrict__ khi) {
  const int gid  = blockIdx.x * 256 + threadIdx.x;
  const int hs   = gid >> 6;
  const int lane = gid & 63;
  if (hs >= NH * NS) return;
  const float scalef = (float)0.04419417382415922;
  const float* ar = alpha + (size_t)hs * NF;
  float s1 = 0.f, s2 = 0.f;
#pragma unroll
  for (int j = 0; j < 8; ++j) {
    float v = ar[lane + 64 * j] * scalef;
    s1 += v; s2 = fmaf(v, v, s2);
  }
  s1 = wave_sum_f32(s1); s2 = wave_sum_f32(s2);
  const float mean = s1 * (1.f / 512.f);
  float var = s2 * (1.f / 512.f) - mean * mean;
  if (var < 0.f) var = 0.f;
  const double e = exp((double)bp[hs]);        // numpy softplus on f32 input
  const float beta = (float)log1p(e);
  const float sig  = sqrtf(var + beta * beta);
  const float that = fmaf(1.281552f, sig, mean);   // 90.04th pct (top 51/512)
  const float w    = 0.30f * sig;
  if (lane == 0) {
    betaf[hs] = beta;
    klo[hs] = f32key(that - w);
    khi[hs] = f32key(that + w);
  }
}

__global__ __launch_bounds__(1024, 8)   // VGPR<=64 -> 2 blocks (32 waves)/CU
void gating_attention_kernel(const float* __restrict__ vals,   // [B,F,H,D]
                             const float* __restrict__ dlg,    // [B,F,H,S]
                             const float* __restrict__ alpha,  // [H,S,F]
                             const float* __restrict__ betap,  // [H,S,1]
                             const float* __restrict__ betaf,  // [H*S] softplus (or null)
                             const unsigned* __restrict__ klo, // [H*S] bracket lo
                             const unsigned* __restrict__ khi, // [H*S] bracket hi
                             float* __restrict__ out)          // [B,S,H,D]
{
#pragma clang fp contract(off)       // numpy does mul THEN add; forbid fma fusion
  __shared__ float dl_t[STILE * LDSF];
  __shared__ uint2 pairs[STILE][64];

  const int blk  = blockIdx.x;       // bh in low 8 bits -> XCD = h (L2 locality)
  const int bh   = blk & 255;
  const int t    = blk >> 8;         // 0..15
  const int b    = bh >> 3;
  const int h    = bh & 7;
  const int s0   = t * STILE;
  const int tid  = threadIdx.x;
  const int w    = tid >> 6;
  const int lane = tid & 63;
  const float scalef = (float)0.04419417382415922;   // f32(1/sqrt(512))

  // ---- stage data_logits tile [16 s][512 f], transposed, full 64B lines ----
#pragma unroll
  for (int cc = 0; cc < 2; ++cc) {
    int i  = cc * 1024 + tid;         // 0..2047
    int f  = i >> 2;                  // 0..511
    int sg = (i & 3) << 2;            // 0,4,8,12
    int fo = f + ((f >> 7) << 3);
    const float4 v4 = *reinterpret_cast<const float4*>(
        dlg + ((((size_t)b * NF + f) * NH + h) * NS + (size_t)(s0 + sg)));
    dl_t[(sg + 0) * LDSF + fo] = v4.x;
    dl_t[(sg + 1) * LDSF + fo] = v4.y;
    dl_t[(sg + 2) * LDSF + fo] = v4.z;
    dl_t[(sg + 3) * LDSF + fo] = v4.w;
  }
  __syncthreads();

  const int s  = s0 + w;
  const int hs = h * NS + s;
  float* row = dl_t + w * LDSF;      // this wave's private swizzled row

  // lane->f mapping: f(g,jj) = 256*g + 4*lane + jj  (g=0,1; jj=0..3)
  const int fb0 = 4 * lane;
  const int off0 = fb0 + ((fb0 >> 7) << 3);
  const int fb1 = 256 + 4 * lane;
  const int off1 = fb1 + ((fb1 >> 7) << 3);

  const float4 a40 = *reinterpret_cast<const float4*>(
      alpha + ((size_t)hs) * NF + fb0);
  const float4 a41 = *reinterpret_cast<const float4*>(
      alpha + ((size_t)hs) * NF + fb1);
  const float4 x40 = *reinterpret_cast<const float4*>(row + off0);
  const float4 x41 = *reinterpret_cast<const float4*>(row + off1);

  float a[8] = {a40.x, a40.y, a40.z, a40.w, a41.x, a41.y, a41.z, a41.w};
  float x[8] = {x40.x, x40.y, x40.z, x40.w, x41.x, x41.y, x41.z, x41.w};

  // ---- mu: numpy-exact pairwise sum / 512 ----
  const float S1 = np_pairwise_sum_512(row, lane);
  const float mu = S1 * (1.0f / 512.0f);

  // ---- var: t=(x-mu); t*t; pairwise sum / 512 ----
  float tv[8];
#pragma unroll
  for (int j = 0; j < 8; ++j) tv[j] = x[j] - mu;
  *reinterpret_cast<float4*>(row + off0) =
      make_float4(tv[0]*tv[0], tv[1]*tv[1], tv[2]*tv[2], tv[3]*tv[3]);
  *reinterpret_cast<float4*>(row + off1) =
      make_float4(tv[4]*tv[4], tv[5]*tv[5], tv[6]*tv[6], tv[7]*tv[7]);
  const float S2  = np_pairwise_sum_512(row, lane);
  const float var = S2 * (1.0f / 512.0f);
  const float stdv = sqrtf(var + 1e-6f) + 1e-6f;   // IEEE f32 sqrt (numpy op)

  // ---- beta ----
  float beta;
  if (betaf) beta = betaf[hs];
  else { double e = exp((double)betap[hs]); beta = (float)log1p(e); }

  // ---- logits: numpy f32 op order; divide via uniform f64 reciprocal ----
  const double rd = 1.0 / (double)stdv;
  float lg[8];
  unsigned key[8];
#pragma unroll
  for (int j = 0; j < 8; ++j) {
    float z  = (float)((double)tv[j] * rd);   // == IEEE f32 div (2^-29 corner aside)
    float m  = beta * z;
    float af = a[j] * scalef;
    float l  = af + m;
    lg[j] = l;
    key[j] = f32key(l);
  }

  auto countGE = [&key](unsigned thr) -> int {
    int c = 0;
#pragma unroll
    for (int j = 0; j < 8; ++j) c += __popcll(__ballot(key[j] >= thr));
    return c;
  };

  // ---- bracket init (precomputed model, or min/max fallback) ----
  unsigned lo, hi;
  if (klo) {
    lo = klo[hs]; hi = khi[hs];
    if (hi <= lo) hi = lo + 1;
  } else {
    unsigned kmax = key[0], kmin = key[0];
#pragma unroll
    for (int j = 1; j < 8; ++j) {
      kmax = key[j] > kmax ? key[j] : kmax;
      kmin = key[j] < kmin ? key[j] : kmin;
    }
#pragma unroll
    for (int o = 32; o > 0; o >>= 1) {
      unsigned om = (unsigned)__shfl_xor((int)kmax, o, 64);
      unsigned on = (unsigned)__shfl_xor((int)kmin, o, 64);
      kmax = om > kmax ? om : kmax;
      kmin = on < kmin ? on : kmin;
    }
    lo = kmin; hi = kmax;
  }

  // ---- guarded exact bisection: T = largest key with count(>=T) >= TOPK ----
  int cl = countGE(lo);
  unsigned step = hi - lo;
  while (cl < TOPK) {                 // bracket entirely above threshold (rare)
    hi = lo;
    lo = (lo >= step) ? (lo - step) : 0u;
    step <<= 1;
    cl = countGE(lo);
  }
  unsigned T; int cnt;
  if (cl == TOPK) { T = lo; cnt = cl; }
  else {
    int ch = countGE(hi);
    while (ch >= TOPK && hi != 0xFFFFFFFFu) {   // bracket below threshold (rare)
      lo = hi; cl = ch;
      unsigned nh = hi + step;
      if (nh < hi) nh = 0xFFFFFFFFu;
      hi = nh; step <<= 1;
      ch = countGE(hi);
    }
    if (ch >= TOPK) { T = hi; cnt = ch; }
    else {
      while (lo < hi) {
        unsigned mid = hi - ((hi - lo) >> 1);
        int cm = countGE(mid);
        if (cm >= TOPK) { lo = mid; cl = cm; if (cm == TOPK) break; }
        else hi = mid - 1;
      }
      T = lo; cnt = cl;
    }
  }
  const bool exact = (cnt == TOPK);

  // ---- keep mask; tie resolution only when needed ----
  bool keep[8];
  if (exact) {
#pragma unroll
    for (int j = 0; j < 8; ++j) keep[j] = (key[j] >= T);
  } else {
    int g = 0;
#pragma unroll
    for (int j = 0; j < 8; ++j) g += __popcll(__ballot(key[j] > T));
    const int need = TOPK - g;
    int cumt = 0;
#pragma unroll
    for (int j = 0; j < 8; ++j) {
      unsigned long long meq = __ballot(key[j] == T);
      int tr = cumt + lane_prefix(meq);
      cumt += __popcll(meq);
      keep[j] = (key[j] > T) || ((key[j] == T) && (tr < need));
    }
  }

  unsigned tb = (T & 0x80000000u) ? (T ^ 0x80000000u) : ~T;
  const float thrf = __uint_as_float(tb);

  // ---- softmax numerators over kept set ----
  float p[8];
  float zs = 0.0f;
#pragma unroll
  for (int j = 0; j < 8; ++j) {
    float e = keep[j] ? __expf(lg[j] - thrf) : 0.0f;
    p[j] = e;
    zs += e;
  }
  // NOTE: zs wave-reduction deferred to after the gather (latency overlap).

  // ---- compact kept (byte-offset, p) pairs into LDS ----
  int base = 0;
#pragma unroll
  for (int j = 0; j < 8; ++j) {
    unsigned long long mk = __ballot(keep[j]);
    int idx = base + lane_prefix(mk);
    if (keep[j]) {
      unsigned f = (unsigned)(((j >> 2) << 8) + 4 * lane + (j & 3));
      pairs[w][idx] = make_uint2(f << 11, __float_as_uint(p[j]));  // f*NH*ND*4 bytes
    }
    base += __popcll(mk);
  }
  if (lane == TOPK) pairs[w][TOPK] = make_uint2(0u, 0u);  // pad slot 51

  // ---- sparse PV gather: 4 k-groups x 16 d-quads, float4 loads ----
  // lane = (g = lane>>4, q = lane&15); group g handles k = 13g .. 13g+12.
  const int g  = lane >> 4;
  const int q  = lane & 15;
  const char* vbase4 =
      (const char*)(vals + (((size_t)b * NF) * NH + h) * ND + 4 * q);
  const uint2* pr = pairs[w] + 13 * g;
  float4 acc4 = make_float4(0.f, 0.f, 0.f, 0.f);
#pragma unroll
  for (int i = 0; i < 13; ++i) {
    uint2 e = pr[i];
    const float4 v4 = *reinterpret_cast<const float4*>(vbase4 + e.x);
    const float pv = __uint_as_float(e.y);
    acc4.x = fmaf(pv, v4.x, acc4.x);
    acc4.y = fmaf(pv, v4.y, acc4.y);
    acc4.z = fmaf(pv, v4.z, acc4.z);
    acc4.w = fmaf(pv, v4.w, acc4.w);
  }
  // combine across the 4 k-groups (xor 16, then 32)
  acc4.x += __shfl_xor(acc4.x, 16, 64);
  acc4.y += __shfl_xor(acc4.y, 16, 64);
  acc4.z += __shfl_xor(acc4.z, 16, 64);
  acc4.w += __shfl_xor(acc4.w, 16, 64);
  acc4.x += __shfl_xor(acc4.x, 32, 64);
  acc4.y += __shfl_xor(acc4.y, 32, 64);
  acc4.z += __shfl_xor(acc4.z, 32, 64);
  acc4.w += __shfl_xor(acc4.w, 32, 64);

  // ---- deferred softmax denominator (overlapped with gather by scheduler) ----
  zs = wave_sum_f32(zs);
  const float rz = 1.0f / zs;

  // lane stores element d = 4q + g
  const float vsel = (g == 0) ? acc4.x : (g == 1) ? acc4.y : (g == 2) ? acc4.z : acc4.w;
  out[(((size_t)b * NS + s) * NH + h) * ND + 4 * q + g] = vsel * rz;
}

extern "C" void kernel_launch(void* const* d_in, const int* in_sizes, int n_in,
                              void* d_out, int out_size, void* d_ws, size_t ws_size,
                              hipStream_t stream) {
  const float* vals  = (const float*)d_in[0];
  const float* dlg   = (const float*)d_in[1];
  const float* alpha = (const float*)d_in[2];
  const float* betap = (const float*)d_in[3];
  float* out = (float*)d_out;

  float* betaf = nullptr; unsigned* klo = nullptr; unsigned* khi = nullptr;
  const size_t need = (size_t)(NH * NS) * 12;   // beta + klo + khi
  if (ws_size >= need) {
    betaf = (float*)d_ws;
    klo   = (unsigned*)((char*)d_ws + (size_t)(NH * NS) * 4);
    khi   = (unsigned*)((char*)d_ws + (size_t)(NH * NS) * 8);
    prep_kernel<<<(NH * NS * 64) / 256, 256, 0, stream>>>(betap, alpha, betaf, klo, khi);
  }

  dim3 grid(NB * NH * (NS / STILE));   // 4096 blocks: one per (b,h,16-row tile)
  dim3 block(1024);
  gating_attention_kernel<<<grid, block, 0, stream>>>(vals, dlg, alpha, betap,
                                                      betaf, klo, khi, out);
}